// Round 2
// baseline (160058.862 us; speedup 1.0000x reference)
//
#include <hip/hip_runtime.h>
#include <math.h>

#define NN 1000
#define INF_ 32
#define H 128
#define M 128
#define DEG 16
#define PP 2
#define OUTF 10
#define MAXM (10 * NN)        // scan length; head <= MAXM
#define QCAP (MAXM + DEG)     // only entries < MAXM are ever read

// ws layout (floats): feats[NN*H] | final[NN*H] | qm[QCAP*M]

__global__ __launch_bounds__(128)
void init_kernel(const float* __restrict__ xa, const float* __restrict__ fm,
                 const float* __restrict__ enc_w, const float* __restrict__ enc_b,
                 const int* __restrict__ nstart_p,
                 float* __restrict__ feats, float* __restrict__ finalv,
                 float* __restrict__ qm) {
    int b = blockIdx.x, t = threadIdx.x;
    float acc = enc_b[t];
    const float* xr = xa + b * INF_;
#pragma unroll
    for (int k = 0; k < INF_; ++k) acc += xr[k] * enc_w[k * H + t];
    feats[b * H + t] = acc;
    finalv[b * H + t] = 0.0f;           // ws is poisoned 0xAA each launch
    if (b < nstart_p[0]) qm[(size_t)b * M + t] = fm[b * M + t];
}

__global__ __launch_bounds__(256, 1)
void seq_kernel(const int* __restrict__ neighbors,
                const float* __restrict__ ns_w, const float* __restrict__ ns_b,
                const float* __restrict__ nm_w, const float* __restrict__ nm_b,
                const float* __restrict__ act_w, const float* __restrict__ act_b,
                const float* __restrict__ dec_w, const float* __restrict__ dec_b,
                const int* __restrict__ nstart_p,
                float* __restrict__ feats, float* __restrict__ finalv,
                float* __restrict__ qm, float* __restrict__ out) {
    __shared__ int   s_qn[QCAP];        // 40064 B — queue node ids in LDS
    __shared__ float s_tact[NN];        // 4000 B  — per-node halting accumulator
    __shared__ __align__(16) float s_x[H + M];
    __shared__ __align__(16) float s_ns[H];
    __shared__ __align__(16) float s_nm[M];
    __shared__ float s_actw[H + M];
    __shared__ float s_nsb[H];
    __shared__ float s_nmb[M];
    __shared__ float s_red[4];
    __shared__ int   s_first[4];
    __shared__ float s_g[H];
    __shared__ float s_lg[PP * OUTF];

    const int t = threadIdx.x;
    const int lane = t & 63, wid = t >> 6;
    const int nstart = nstart_p[0];

    for (int i = t; i < NN; i += 256) s_tact[i] = 0.0f;
    for (int i = t; i < nstart; i += 256) s_qn[i] = i;
    s_actw[t] = act_w[t];
    if (t < H) { s_nsb[t] = ns_b[t]; s_nmb[t] = nm_b[t]; }
    const float actb = act_b[0];
    __syncthreads();

    int head = 0, tail = nstart;
    for (;;) {
        // ---- batched scan for the next unhalted pop ----
        int nh = -1;
        while (head < tail && head < MAXM) {
            const int i = head + t;
            const bool ok = (i < tail) && (i < MAXM);
            const int ii = (i < QCAP) ? i : 0;
            const int nodei = s_qn[ii];
            const bool isproc = ok && (s_tact[nodei] <= 1.0f - 1e-7f);
            const unsigned long long mask = __ballot(isproc);
            if (lane == 0)
                s_first[wid] = mask ? (wid * 64 + (__ffsll((unsigned long long)mask) - 1))
                                    : 0x7fffffff;
            __syncthreads();
            const int rel = min(min(s_first[0], s_first[1]),
                                min(s_first[2], s_first[3]));
            __syncthreads();                 // protect s_first reuse
            if (rel != 0x7fffffff) { nh = head + rel; break; }
            head += 256;
        }
        if (nh < 0) break;
        head = nh;

        const int node = s_qn[head];         // uniform
        const float ta = s_tact[node];

        // ---- stage 0: stage x = concat(feats[node], qm[head]) ----
        if (t < H) s_x[t] = feats[node * H + t];
        else       s_x[t] = qm[(size_t)head * M + (t - H)];
        int nbr = 0;
        if (t < DEG) nbr = neighbors[node * DEG + t];   // overlap with stage 1
        __syncthreads();

        // ---- stage 1: ns col (t<H) / nm msg-half (t>=H); gate reduce overlapped ----
        float p = s_x[t] * s_actw[t];
        float acc;
        if (t < H) {
            const float* w = ns_w + t;
            float a0=0,a1=0,a2=0,a3=0,a4=0,a5=0,a6=0,a7=0;
#pragma unroll
            for (int k = 0; k < H + M; k += 8) {
                a0 += s_x[k+0] * w[(k+0)*H];
                a1 += s_x[k+1] * w[(k+1)*H];
                a2 += s_x[k+2] * w[(k+2)*H];
                a3 += s_x[k+3] * w[(k+3)*H];
                a4 += s_x[k+4] * w[(k+4)*H];
                a5 += s_x[k+5] * w[(k+5)*H];
                a6 += s_x[k+6] * w[(k+6)*H];
                a7 += s_x[k+7] * w[(k+7)*H];
            }
            acc = ((a0+a1)+(a2+a3)) + ((a4+a5)+(a6+a7));
        } else {
            const int j = t - H;
            const float* w = nm_w + (size_t)H * M + j;
            float a0=0,a1=0,a2=0,a3=0,a4=0,a5=0,a6=0,a7=0;
#pragma unroll
            for (int k = 0; k < M; k += 8) {
                a0 += s_x[H+k+0] * w[(k+0)*M];
                a1 += s_x[H+k+1] * w[(k+1)*M];
                a2 += s_x[H+k+2] * w[(k+2)*M];
                a3 += s_x[H+k+3] * w[(k+3)*M];
                a4 += s_x[H+k+4] * w[(k+4)*M];
                a5 += s_x[H+k+5] * w[(k+5)*M];
                a6 += s_x[H+k+6] * w[(k+6)*M];
                a7 += s_x[H+k+7] * w[(k+7)*M];
            }
            acc = ((a0+a1)+(a2+a3)) + ((a4+a5)+(a6+a7));
        }
#pragma unroll
        for (int off = 32; off > 0; off >>= 1) p += __shfl_down(p, off, 64);
        if (lane == 0) s_red[wid] = p;
        float nsval = 0.0f;
        if (t < H) { nsval = fmaxf(acc + s_nsb[t], 0.0f); s_ns[t] = nsval; }
        __syncthreads();

        // ---- stage 2: gate; nm ns-half (t>=H); feats/final update (t<H) ----
        const float z = s_red[0] + s_red[1] + s_red[2] + s_red[3] + actb;
        const float cand = 1.0f / (1.0f + expf(-z));
        const float new_act = (ta + cand > 1.0f) ? (1.0f - ta) : cand;
        if (t >= H) {
            const int j = t - H;
            const float* w = nm_w + j;
            float a0=0,a1=0,a2=0,a3=0,a4=0,a5=0,a6=0,a7=0;
#pragma unroll
            for (int k = 0; k < H; k += 8) {
                a0 += s_ns[k+0] * w[(k+0)*M];
                a1 += s_ns[k+1] * w[(k+1)*M];
                a2 += s_ns[k+2] * w[(k+2)*M];
                a3 += s_ns[k+3] * w[(k+3)*M];
                a4 += s_ns[k+4] * w[(k+4)*M];
                a5 += s_ns[k+5] * w[(k+5)*M];
                a6 += s_ns[k+6] * w[(k+6)*M];
                a7 += s_ns[k+7] * w[(k+7)*M];
            }
            s_nm[j] = acc + s_nmb[j] + (((a0+a1)+(a2+a3)) + ((a4+a5)+(a6+a7)));
        } else {
            feats[node * H + t] = nsval;
            finalv[node * H + t] += nsval * new_act;
        }
        if (t < DEG) { const int q = tail + t; if (q < QCAP) s_qn[q] = nbr; }
        if (t == 0) s_tact[node] = ta + new_act;
        __syncthreads();

        // ---- stage 3: enqueue 16 copies of nm (float4, coalesced) ----
        {
            const float4* nm4 = (const float4*)s_nm;
            float4* qm4 = (float4*)qm;
            const int c4 = t & 31;            // 32 float4 per row
            const float4 v = nm4[c4];
#pragma unroll
            for (int r = (t >> 5); r < DEG; r += 8) {
                const int q = tail + r;
                if (q < QCAP) qm4[(size_t)q * 32 + c4] = v;
            }
        }
        tail += DEG;
        head += 1;
        __syncthreads();   // qm/s_qn/s_tact visible before next scan/pop
    }

    // ---- readout: g = colsum(final); logits = g @ dec_w + dec_b; log_softmax ----
    __syncthreads();
    if (t < H) {
        float g0 = 0, g1 = 0, g2 = 0, g3 = 0;
        for (int n = 0; n < NN; n += 4) {
            g0 += finalv[(n + 0) * H + t];
            g1 += finalv[(n + 1) * H + t];
            g2 += finalv[(n + 2) * H + t];
            g3 += finalv[(n + 3) * H + t];
        }
        s_g[t] = (g0 + g1) + (g2 + g3);
    }
    __syncthreads();
    if (t < PP * OUTF) {
        const int pp = t / OUTF, o = t % OUTF;
        float acc = dec_b[pp * OUTF + o];
        for (int h = 0; h < H; ++h) acc += s_g[h] * dec_w[(pp * H + h) * OUTF + o];
        s_lg[t] = acc;
    }
    __syncthreads();
    if (t < PP * OUTF) {
        const int pp = t / OUTF;
        float mx = -INFINITY;
        for (int o = 0; o < OUTF; ++o) mx = fmaxf(mx, s_lg[pp * OUTF + o]);
        float s = 0.0f;
        for (int o = 0; o < OUTF; ++o) s += expf(s_lg[pp * OUTF + o] - mx);
        out[t] = s_lg[t] - (mx + logf(s));
    }
}

extern "C" void kernel_launch(void* const* d_in, const int* in_sizes, int n_in,
                              void* d_out, int out_size, void* d_ws, size_t ws_size,
                              hipStream_t stream) {
    const float* xa        = (const float*)d_in[0];
    const float* fm        = (const float*)d_in[1];
    const int*   neighbors = (const int*)  d_in[2];
    const int*   nstart_p  = (const int*)  d_in[3];
    const float* enc_w     = (const float*)d_in[4];
    const float* enc_b     = (const float*)d_in[5];
    const float* ns_w      = (const float*)d_in[6];
    const float* ns_b      = (const float*)d_in[7];
    const float* nm_w      = (const float*)d_in[8];
    const float* nm_b      = (const float*)d_in[9];
    const float* act_w     = (const float*)d_in[10];
    const float* act_b     = (const float*)d_in[11];
    const float* dec_w     = (const float*)d_in[12];
    const float* dec_b     = (const float*)d_in[13];
    float* out = (float*)d_out;

    float* feats  = (float*)d_ws;
    float* finalv = feats + NN * H;
    float* qm     = finalv + NN * H;   // QCAP*M floats ≈ 5.1 MB

    init_kernel<<<NN, 128, 0, stream>>>(xa, fm, enc_w, enc_b, nstart_p,
                                        feats, finalv, qm);
    seq_kernel<<<1, 256, 0, stream>>>(neighbors, ns_w, ns_b, nm_w, nm_b,
                                      act_w, act_b, dec_w, dec_b, nstart_p,
                                      feats, finalv, qm, out);
}

// Round 3
// 9700.668 us; speedup vs baseline: 16.4998x; 16.4998x over previous
//
#include <hip/hip_runtime.h>
#include <math.h>

#define NN 1000
#define INF_ 32
#define H 128
#define M 128
#define DEG 16
#define PP 2
#define OUTF 10
#define MAXM (10 * NN)        // scan length; head <= MAXM
#define QCAP (MAXM + DEG)     // only entries < MAXM are ever read
#define NT 512

// ws layout (floats): feats[NN*H] | final[NN*H] | qm[QCAP*M]

__global__ __launch_bounds__(128)
void init_kernel(const float* __restrict__ xa, const float* __restrict__ fm,
                 const float* __restrict__ enc_w, const float* __restrict__ enc_b,
                 const int* __restrict__ nstart_p,
                 float* __restrict__ feats, float* __restrict__ finalv,
                 float* __restrict__ qm) {
    int b = blockIdx.x, t = threadIdx.x;
    float acc = enc_b[t];
    const float* xr = xa + b * INF_;
#pragma unroll
    for (int k = 0; k < INF_; ++k) acc += xr[k] * enc_w[k * H + t];
    feats[b * H + t] = acc;
    finalv[b * H + t] = 0.0f;           // ws is poisoned 0xAA each launch
    if (b < nstart_p[0]) qm[(size_t)b * M + t] = fm[b * M + t];
}

// 512 threads: col = t&127, kc = t>>7 (4 K-chunks). Weights permanently in
// registers: wns[64] = ns_w[kc*64+j][col]; wnmA[32] = nm_w[128+kc*32+j][col]
// (msg half); wnmB[32] = nm_w[kc*32+j][col] (ns half). 128 weight VGPRs/thread.
__global__ __launch_bounds__(NT, 2)
void seq_kernel(const int* __restrict__ neighbors,
                const float* __restrict__ ns_w, const float* __restrict__ ns_b,
                const float* __restrict__ nm_w, const float* __restrict__ nm_b,
                const float* __restrict__ act_w, const float* __restrict__ act_b,
                const float* __restrict__ dec_w, const float* __restrict__ dec_b,
                const int* __restrict__ nstart_p,
                float* __restrict__ feats, float* __restrict__ finalv,
                float* __restrict__ qm, float* __restrict__ out) {
    __shared__ int   s_qn[QCAP];        // 40064 B — queue node ids
    __shared__ float s_tact[NN];        // 4000 B  — per-node halting acc
    __shared__ __align__(16) float s_x[H + M];
    __shared__ __align__(16) float s_ns[H];
    __shared__ __align__(16) float s_nm[M];
    __shared__ __align__(16) float s_pns[4 * H];   // split-K partials (ns)
    __shared__ __align__(16) float s_pnm[4 * M];   // split-K partials (nm)
    __shared__ float s_actw[H + M];
    __shared__ float s_nsb[H];
    __shared__ float s_nmb[M];
    __shared__ float s_red[4];
    __shared__ int   s_first[8];
    __shared__ float s_g[H];
    __shared__ float s_lg[PP * OUTF];

    const int t = threadIdx.x;
    const int lane = t & 63, wid = t >> 6;
    const int col = t & 127, kc = t >> 7;
    const int nstart = nstart_p[0];

    // ---- one-time: weights into registers (fully unrolled => promoted) ----
    float wns[64], wnmA[32], wnmB[32];
    {
        const float* pw = ns_w + (size_t)(kc * 64) * H + col;
#pragma unroll
        for (int j = 0; j < 64; ++j) wns[j] = pw[(size_t)j * H];
        const float* pa = nm_w + (size_t)(128 + kc * 32) * M + col;
#pragma unroll
        for (int j = 0; j < 32; ++j) wnmA[j] = pa[(size_t)j * M];
        const float* pb = nm_w + (size_t)(kc * 32) * M + col;
#pragma unroll
        for (int j = 0; j < 32; ++j) wnmB[j] = pb[(size_t)j * M];
    }

    for (int i = t; i < NN; i += NT) s_tact[i] = 0.0f;
    for (int i = t; i < nstart; i += NT) s_qn[i] = i;
    if (t < H + M) s_actw[t] = act_w[t];
    if (t < H) { s_nsb[t] = ns_b[t]; s_nmb[t] = nm_b[t]; }
    const float actb = act_b[0];
    __syncthreads();

    int head = 0, tail = nstart;
    for (;;) {
        // ---- batched ballot scan for next unhalted pop (512-wide) ----
        int nh = -1;
        while (head < tail && head < MAXM) {
            const int i = head + t;
            const bool ok = (i < tail) && (i < MAXM);
            const int ii = (i < QCAP) ? i : 0;
            const int nodei = s_qn[ii];
            const bool isproc = ok && (s_tact[nodei] <= 1.0f - 1e-7f);
            const unsigned long long mask = __ballot(isproc);
            if (lane == 0)
                s_first[wid] = mask ? (wid * 64 + (__ffsll(mask) - 1))
                                    : 0x7fffffff;
            __syncthreads();
            int rel = s_first[0];
#pragma unroll
            for (int w = 1; w < 8; ++w) rel = min(rel, s_first[w]);
            __syncthreads();                 // protect s_first reuse
            if (rel != 0x7fffffff) { nh = head + rel; break; }
            head += NT;
        }
        if (nh < 0) break;
        head = nh;

        const int node = s_qn[head];         // uniform
        const float ta = s_tact[node];

        // ---- stage 0: x = concat(feats[node], qm[head]); prefetch nbrs ----
        if (t < H) s_x[t] = feats[node * H + t];
        else if (t < H + M) s_x[t] = qm[(size_t)head * M + (t - H)];
        int nbr = 0;
        if (t < DEG) nbr = neighbors[node * DEG + t];
        __syncthreads();

        // ---- stage 1: ns partials + nm msg-half partials + gate reduce ----
        float accn;
        {
            const int k0 = kc * 64;
            float a0 = 0, a1 = 0, a2 = 0, a3 = 0;
#pragma unroll
            for (int j = 0; j < 64; j += 4) {
                a0 += s_x[k0 + j + 0] * wns[j + 0];
                a1 += s_x[k0 + j + 1] * wns[j + 1];
                a2 += s_x[k0 + j + 2] * wns[j + 2];
                a3 += s_x[k0 + j + 3] * wns[j + 3];
            }
            accn = (a0 + a1) + (a2 + a3);
        }
        s_pns[kc * H + col] = accn;
        float accm;
        {
            const int k0 = 128 + kc * 32;
            float a0 = 0, a1 = 0;
#pragma unroll
            for (int j = 0; j < 32; j += 2) {
                a0 += s_x[k0 + j + 0] * wnmA[j + 0];
                a1 += s_x[k0 + j + 1] * wnmA[j + 1];
            }
            accm = a0 + a1;
        }
        if (t < H + M) {                      // gate: bit-identical to R1
            float p = s_x[t] * s_actw[t];
#pragma unroll
            for (int off = 32; off > 0; off >>= 1) p += __shfl_down(p, off, 64);
            if (lane == 0) s_red[wid] = p;
        }
        __syncthreads();

        // ---- stage 2: gate final; ns finalize; feats/final; enqueue ids ----
        const float z = s_red[0] + s_red[1] + s_red[2] + s_red[3] + actb;
        const float cand = 1.0f / (1.0f + expf(-z));
        const float new_act = (ta + cand > 1.0f) ? (1.0f - ta) : cand;
        if (t < H) {
            const float nsval = fmaxf(
                ((s_pns[t] + s_pns[H + t]) + (s_pns[2 * H + t] + s_pns[3 * H + t]))
                + s_nsb[t], 0.0f);
            s_ns[t] = nsval;
            feats[node * H + t] = nsval;
            finalv[node * H + t] += nsval * new_act;
        }
        if (t < DEG) { const int q = tail + t; if (q < QCAP) s_qn[q] = nbr; }
        if (t == 0) s_tact[node] = ta + new_act;
        __syncthreads();

        // ---- stage 3: nm ns-half partials (all 512 threads) ----
        {
            const int k0 = kc * 32;
            float a0 = 0, a1 = 0;
#pragma unroll
            for (int j = 0; j < 32; j += 2) {
                a0 += s_ns[k0 + j + 0] * wnmB[j + 0];
                a1 += s_ns[k0 + j + 1] * wnmB[j + 1];
            }
            accm += a0 + a1;
        }
        s_pnm[kc * M + col] = accm;
        __syncthreads();

        // ---- stage 4: nm finalize ----
        if (t < M)
            s_nm[t] = ((s_pnm[t] + s_pnm[M + t]) + (s_pnm[2 * M + t] + s_pnm[3 * M + t]))
                      + s_nmb[t];
        __syncthreads();

        // ---- stage 5: enqueue 16 rows of nm (one float4 store/thread) ----
        {
            const float4* nm4 = (const float4*)s_nm;
            float4* qm4 = (float4*)qm;
            const int r = t >> 5, c4 = t & 31;
            const int q = tail + r;
            if (q < QCAP) qm4[(size_t)q * 32 + c4] = nm4[c4];
        }
        tail += DEG;
        head += 1;
        __syncthreads();   // qm/s_qn/s_tact visible before next scan
    }

    // ---- readout: g = colsum(final); logits = g@dec_w+dec_b; log_softmax ----
    __syncthreads();
    if (t < H) {
        float g0 = 0, g1 = 0, g2 = 0, g3 = 0;
        for (int n = 0; n < NN; n += 4) {
            g0 += finalv[(n + 0) * H + t];
            g1 += finalv[(n + 1) * H + t];
            g2 += finalv[(n + 2) * H + t];
            g3 += finalv[(n + 3) * H + t];
        }
        s_g[t] = (g0 + g1) + (g2 + g3);
    }
    __syncthreads();
    if (t < PP * OUTF) {
        const int pp = t / OUTF, o = t % OUTF;
        float acc = dec_b[pp * OUTF + o];
        for (int h = 0; h < H; ++h) acc += s_g[h] * dec_w[(pp * H + h) * OUTF + o];
        s_lg[t] = acc;
    }
    __syncthreads();
    if (t < PP * OUTF) {
        const int pp = t / OUTF;
        float mx = -INFINITY;
        for (int o = 0; o < OUTF; ++o) mx = fmaxf(mx, s_lg[pp * OUTF + o]);
        float s = 0.0f;
        for (int o = 0; o < OUTF; ++o) s += expf(s_lg[pp * OUTF + o] - mx);
        out[t] = s_lg[t] - (mx + logf(s));
    }
}

extern "C" void kernel_launch(void* const* d_in, const int* in_sizes, int n_in,
                              void* d_out, int out_size, void* d_ws, size_t ws_size,
                              hipStream_t stream) {
    const float* xa        = (const float*)d_in[0];
    const float* fm        = (const float*)d_in[1];
    const int*   neighbors = (const int*)  d_in[2];
    const int*   nstart_p  = (const int*)  d_in[3];
    const float* enc_w     = (const float*)d_in[4];
    const float* enc_b     = (const float*)d_in[5];
    const float* ns_w      = (const float*)d_in[6];
    const float* ns_b      = (const float*)d_in[7];
    const float* nm_w      = (const float*)d_in[8];
    const float* nm_b      = (const float*)d_in[9];
    const float* act_w     = (const float*)d_in[10];
    const float* act_b     = (const float*)d_in[11];
    const float* dec_w     = (const float*)d_in[12];
    const float* dec_b     = (const float*)d_in[13];
    float* out = (float*)d_out;

    float* feats  = (float*)d_ws;
    float* finalv = feats + NN * H;
    float* qm     = finalv + NN * H;   // QCAP*M floats ≈ 5.1 MB

    init_kernel<<<NN, 128, 0, stream>>>(xa, fm, enc_w, enc_b, nstart_p,
                                        feats, finalv, qm);
    seq_kernel<<<1, NT, 0, stream>>>(neighbors, ns_w, ns_b, nm_w, nm_b,
                                     act_w, act_b, dec_w, dec_b, nstart_p,
                                     feats, finalv, qm, out);
}

// Round 4
// 6217.072 us; speedup vs baseline: 25.7451x; 1.5603x over previous
//
#include <hip/hip_runtime.h>
#include <math.h>

#define NN 1000
#define INF_ 32
#define H 128
#define M 128
#define DEG 16
#define PP 2
#define OUTF 10
#define MAXM (10 * NN)        // scan length; head <= MAXM
#define QCAP (MAXM + DEG)     // only entries < MAXM are ever read
#define NT 512
#define BMAX 16               // max procs per parallel batch

// ws layout (floats): feats[NN*H] | final[NN*H] | qm[QCAP*M]

__global__ __launch_bounds__(128)
void init_kernel(const float* __restrict__ xa, const float* __restrict__ fm,
                 const float* __restrict__ enc_w, const float* __restrict__ enc_b,
                 const int* __restrict__ nstart_p,
                 float* __restrict__ feats, float* __restrict__ finalv,
                 float* __restrict__ qm) {
    int b = blockIdx.x, t = threadIdx.x;
    float acc = enc_b[t];
    const float* xr = xa + b * INF_;
#pragma unroll
    for (int k = 0; k < INF_; ++k) acc += xr[k] * enc_w[k * H + t];
    feats[b * H + t] = acc;
    finalv[b * H + t] = 0.0f;           // ws is poisoned 0xAA each launch
    if (b < nstart_p[0]) qm[(size_t)b * M + t] = fm[b * M + t];
}

// Batched sequential ACT loop. Window-scan finds a prefix of pops whose
// parallel execution against batch-start state equals reference-sequential
// execution: cut before the first proc-candidate whose node was already
// proc'd earlier in the window (tact monotone => halted entries never flip).
__global__ __launch_bounds__(NT, 2)
void seq_kernel(const int* __restrict__ neighbors,
                const float* __restrict__ ns_w, const float* __restrict__ ns_b,
                const float* __restrict__ nm_w, const float* __restrict__ nm_b,
                const float* __restrict__ act_w, const float* __restrict__ act_b,
                const float* __restrict__ dec_w, const float* __restrict__ dec_b,
                const int* __restrict__ nstart_p,
                float* __restrict__ feats, float* __restrict__ finalv,
                float* __restrict__ qm, float* __restrict__ out) {
    __shared__ unsigned short s_qn[QCAP];            // 20032 B (ids < 1000)
    __shared__ float s_tact[NN];                     // 4000 B
    __shared__ int   s_mark[NN];                     // 4000 B
    __shared__ __align__(16) float s_X[BMAX][H + M]; // 16 KB batch inputs
    __shared__ __align__(16) float s_NS[BMAX][H];    // 8 KB
    __shared__ __align__(16) float s_NM[BMAX][M];    // 8 KB
    __shared__ float s_actw[H + M];
    __shared__ float s_nsb[H];
    __shared__ float s_nmb[M];
    __shared__ float s_z[BMAX];
    __shared__ float s_newact[BMAX];
    __shared__ int   s_pidx[BMAX];
    __shared__ int   s_pnode[BMAX];
    __shared__ int   s_wcnt[8];
    __shared__ int   s_wconf[8];
    __shared__ int   s_wcnt2[8];
    __shared__ int   s_cut2;
    __shared__ float s_g[H];
    __shared__ float s_lg[PP * OUTF];

    const int t = threadIdx.x;
    const int lane = t & 63, wid = t >> 6;
    const int col = t & 127, g = t >> 7;             // matvec mapping
    const int nstart = nstart_p[0];

    for (int i = t; i < NN; i += NT) { s_tact[i] = 0.0f; s_mark[i] = 0x7fffffff; }
    for (int i = t; i < nstart; i += NT) s_qn[i] = (unsigned short)i;
    if (t < H + M) s_actw[t] = act_w[t];
    if (t < H) { s_nsb[t] = ns_b[t]; s_nmb[t] = nm_b[t]; }
    const float actb = act_b[0];
    __syncthreads();

    int head = 0, tail = nstart;
    while (head < tail && head < MAXM) {
        // ---------------- window scan ----------------
        const int lim = min(tail, MAXM);
        const int W = min(NT, lim - head);
        const bool in = (t < W);
        int node = 0; bool proc0 = false;
        if (in) {
            node = (int)s_qn[head + t];
            proc0 = (s_tact[node] <= 1.0f - 1e-7f);
        }
        if (proc0) atomicMin(&s_mark[node], t);
        __syncthreads();                             // S1: marks visible
        const bool conf = proc0 && (s_mark[node] < t);
        const unsigned long long mproc = __ballot(proc0);
        const unsigned long long mconf = __ballot(conf);
        if (lane == 0) {
            s_wcnt[wid]  = __popcll(mproc);
            s_wconf[wid] = mconf ? (wid * 64 + __ffsll(mconf) - 1) : 0x7fffffff;
        }
        if (t == 0) s_cut2 = 0x7fffffff;
        __syncthreads();                             // S2
        int cut1 = s_wconf[0];
#pragma unroll
        for (int w = 1; w < 8; ++w) cut1 = min(cut1, s_wconf[w]);
        int pre = 0;
#pragma unroll
        for (int w = 0; w < 8; ++w) pre += (w < wid) ? s_wcnt[w] : 0;
        const int rank = pre + __popcll(mproc & ((1ull << lane) - 1ull));
        if (proc0 && rank == BMAX) s_cut2 = t;       // unique writer
        __syncthreads();                             // S3
        const int cutN = min(min(cut1, s_cut2), W);  // >= 1 always
        const bool proc = proc0 && (t < cutN);
        const unsigned long long mfin = __ballot(proc);
        if (lane == 0) s_wcnt2[wid] = __popcll(mfin);
        if (proc) { s_pidx[rank] = t; s_pnode[rank] = node; }
        if (proc0) s_mark[node] = 0x7fffffff;        // reset (benign same-value race)
        __syncthreads();                             // S4
        int P = 0;
#pragma unroll
        for (int w = 0; w < 8; ++w) P += s_wcnt2[w];

        if (P > 0) {
            // ---- load batch inputs X[r] = concat(feats[node_r], qm[head_r]) ----
            for (int idx = t; idx < P * 64; idx += NT) {
                const int r = idx >> 6, c4 = idx & 63;
                const int nr = s_pnode[r];
                const int hp = head + s_pidx[r];
                float4 v;
                if (c4 < 32) v = ((const float4*)(feats + (size_t)nr * H))[c4];
                else         v = ((const float4*)(qm + (size_t)hp * M))[c4 - 32];
                ((float4*)&s_X[r][0])[c4] = v;
            }
            __syncthreads();                         // S5: X ready

            // ---- gate partials: r = t>>5, 8 elements per lane-of-32 ----
            {
                const int r = t >> 5, sg = t & 31;
                float p = 0.0f;
                if (r < P) {
                    const float* xr = &s_X[r][0];
#pragma unroll
                    for (int j = 0; j < 8; ++j)
                        p += xr[sg * 8 + j] * s_actw[sg * 8 + j];
                }
#pragma unroll
                for (int off = 16; off > 0; off >>= 1) p += __shfl_down(p, off, 32);
                if (sg == 0 && r < P) s_z[r] = p;
            }

            // ---- matvecs: thread (col,g) computes rows r = g,g+4,g+8,g+12 ----
            float an0=0,an1=0,an2=0,an3=0, am0=0,am1=0,am2=0,am3=0;
            {
                const float* wn = ns_w + col;
                const float* wm = nm_w + col;
                const float4* X0 = (const float4*)&s_X[(g    ) & (BMAX-1)][0];
                const float4* X1 = (const float4*)&s_X[(g + 4) & (BMAX-1)][0];
                const float4* X2 = (const float4*)&s_X[(g + 8) & (BMAX-1)][0];
                const float4* X3 = (const float4*)&s_X[(g +12) & (BMAX-1)][0];
#pragma unroll 4
                for (int j4 = 0; j4 < 32; ++j4) {    // k in [0,128): ns only
                    const int j = j4 * 4;
                    const float w0 = wn[(j+0)*H], w1 = wn[(j+1)*H];
                    const float w2 = wn[(j+2)*H], w3 = wn[(j+3)*H];
                    const float4 x0 = X0[j4], x1 = X1[j4], x2 = X2[j4], x3 = X3[j4];
                    an0 += x0.x*w0 + x0.y*w1 + x0.z*w2 + x0.w*w3;
                    an1 += x1.x*w0 + x1.y*w1 + x1.z*w2 + x1.w*w3;
                    an2 += x2.x*w0 + x2.y*w1 + x2.z*w2 + x2.w*w3;
                    an3 += x3.x*w0 + x3.y*w1 + x3.z*w2 + x3.w*w3;
                }
#pragma unroll 4
                for (int j4 = 32; j4 < 64; ++j4) {   // k in [128,256): ns + nm msg-half
                    const int j = j4 * 4;
                    const float w0 = wn[(j+0)*H], w1 = wn[(j+1)*H];
                    const float w2 = wn[(j+2)*H], w3 = wn[(j+3)*H];
                    const float m0 = wm[(j+0)*M], m1 = wm[(j+1)*M];
                    const float m2 = wm[(j+2)*M], m3 = wm[(j+3)*M];
                    const float4 x0 = X0[j4], x1 = X1[j4], x2 = X2[j4], x3 = X3[j4];
                    an0 += x0.x*w0 + x0.y*w1 + x0.z*w2 + x0.w*w3;
                    an1 += x1.x*w0 + x1.y*w1 + x1.z*w2 + x1.w*w3;
                    an2 += x2.x*w0 + x2.y*w1 + x2.z*w2 + x2.w*w3;
                    an3 += x3.x*w0 + x3.y*w1 + x3.z*w2 + x3.w*w3;
                    am0 += x0.x*m0 + x0.y*m1 + x0.z*m2 + x0.w*m3;
                    am1 += x1.x*m0 + x1.y*m1 + x1.z*m2 + x1.w*m3;
                    am2 += x2.x*m0 + x2.y*m1 + x2.z*m2 + x2.w*m3;
                    am3 += x3.x*m0 + x3.y*m1 + x3.z*m2 + x3.w*m3;
                }
            }
            const float nsb = s_nsb[col];
            const float nsv0 = fmaxf(an0 + nsb, 0.0f);
            const float nsv1 = fmaxf(an1 + nsb, 0.0f);
            const float nsv2 = fmaxf(an2 + nsb, 0.0f);
            const float nsv3 = fmaxf(an3 + nsb, 0.0f);
            if (g      < P) s_NS[g     ][col] = nsv0;
            if (g +  4 < P) s_NS[g +  4][col] = nsv1;
            if (g +  8 < P) s_NS[g +  8][col] = nsv2;
            if (g + 12 < P) s_NS[g + 12][col] = nsv3;
            __syncthreads();                         // S6: NS + s_z ready

            // ---- gate finalize + tact update (distinct nodes => safe) ----
            if (t < P) {
                const float z = s_z[t] + actb;
                const float cand = 1.0f / (1.0f + expf(-z));
                const int nr = s_pnode[t];
                const float ta = s_tact[nr];
                const float na = (ta + cand > 1.0f) ? (1.0f - ta) : cand;
                s_newact[t] = na;
                s_tact[nr] = ta + na;
            }
            // ---- qn enqueue ----
            if (t < P * DEG) {
                const int r = t >> 4;                // q = tail + 16r + d = tail + t
                const int q = tail + t;
                if (q < QCAP)
                    s_qn[q] = (unsigned short)neighbors[s_pnode[r] * DEG + (t & 15)];
            }
            // ---- nm ns-half: am += NS @ nm_w[0:128] ----
            {
                const float* wm = nm_w + col;
                const float4* N0 = (const float4*)&s_NS[(g    ) & (BMAX-1)][0];
                const float4* N1 = (const float4*)&s_NS[(g + 4) & (BMAX-1)][0];
                const float4* N2 = (const float4*)&s_NS[(g + 8) & (BMAX-1)][0];
                const float4* N3 = (const float4*)&s_NS[(g +12) & (BMAX-1)][0];
#pragma unroll 4
                for (int k4 = 0; k4 < 32; ++k4) {
                    const int k = k4 * 4;
                    const float m0 = wm[(k+0)*M], m1 = wm[(k+1)*M];
                    const float m2 = wm[(k+2)*M], m3 = wm[(k+3)*M];
                    const float4 y0 = N0[k4], y1 = N1[k4], y2 = N2[k4], y3 = N3[k4];
                    am0 += y0.x*m0 + y0.y*m1 + y0.z*m2 + y0.w*m3;
                    am1 += y1.x*m0 + y1.y*m1 + y1.z*m2 + y1.w*m3;
                    am2 += y2.x*m0 + y2.y*m1 + y2.z*m2 + y2.w*m3;
                    am3 += y3.x*m0 + y3.y*m1 + y3.z*m2 + y3.w*m3;
                }
            }
            const float nmb = s_nmb[col];
            if (g      < P) s_NM[g     ][col] = am0 + nmb;
            if (g +  4 < P) s_NM[g +  4][col] = am1 + nmb;
            if (g +  8 < P) s_NM[g +  8][col] = am2 + nmb;
            if (g + 12 < P) s_NM[g + 12][col] = am3 + nmb;
            __syncthreads();                         // S7: newact + NM ready

            // ---- feats / finalv updates (distinct rows) ----
            if (g      < P) { const int nr = s_pnode[g     ];
                feats[(size_t)nr*H+col] = nsv0;
                finalv[(size_t)nr*H+col] += nsv0 * s_newact[g     ]; }
            if (g +  4 < P) { const int nr = s_pnode[g +  4];
                feats[(size_t)nr*H+col] = nsv1;
                finalv[(size_t)nr*H+col] += nsv1 * s_newact[g +  4]; }
            if (g +  8 < P) { const int nr = s_pnode[g +  8];
                feats[(size_t)nr*H+col] = nsv2;
                finalv[(size_t)nr*H+col] += nsv2 * s_newact[g +  8]; }
            if (g + 12 < P) { const int nr = s_pnode[g + 12];
                feats[(size_t)nr*H+col] = nsv3;
                finalv[(size_t)nr*H+col] += nsv3 * s_newact[g + 12]; }

            // ---- qm enqueue: P*16 rows, float4 coalesced ----
            {
                float4* qm4 = (float4*)qm;
                const int total = P * DEG * 32;
                for (int idx = t; idx < total; idx += NT) {
                    const int c4 = idx & 31;
                    const int row = idx >> 5;        // 0 .. P*16-1
                    const int r = row >> 4;
                    const int q = tail + row;
                    if (q < QCAP)
                        qm4[(size_t)q * 32 + c4] = ((const float4*)&s_NM[r][0])[c4];
                }
            }
            tail += DEG * P;
        }
        head += cutN;
        __syncthreads();                             // S8: state ready for next window
    }

    // ---- readout: g = colsum(final); logits = g@dec_w+dec_b; log_softmax ----
    if (t < H) {
        float g0 = 0, g1 = 0, g2 = 0, g3 = 0;
        for (int n = 0; n < NN; n += 4) {
            g0 += finalv[(n + 0) * H + t];
            g1 += finalv[(n + 1) * H + t];
            g2 += finalv[(n + 2) * H + t];
            g3 += finalv[(n + 3) * H + t];
        }
        s_g[t] = (g0 + g1) + (g2 + g3);
    }
    __syncthreads();
    if (t < PP * OUTF) {
        const int pp = t / OUTF, o = t % OUTF;
        float acc = dec_b[pp * OUTF + o];
        for (int h = 0; h < H; ++h) acc += s_g[h] * dec_w[(pp * H + h) * OUTF + o];
        s_lg[t] = acc;
    }
    __syncthreads();
    if (t < PP * OUTF) {
        const int pp = t / OUTF;
        float mx = -INFINITY;
        for (int o = 0; o < OUTF; ++o) mx = fmaxf(mx, s_lg[pp * OUTF + o]);
        float s = 0.0f;
        for (int o = 0; o < OUTF; ++o) s += expf(s_lg[pp * OUTF + o] - mx);
        out[t] = s_lg[t] - (mx + logf(s));
    }
}

extern "C" void kernel_launch(void* const* d_in, const int* in_sizes, int n_in,
                              void* d_out, int out_size, void* d_ws, size_t ws_size,
                              hipStream_t stream) {
    const float* xa        = (const float*)d_in[0];
    const float* fm        = (const float*)d_in[1];
    const int*   neighbors = (const int*)  d_in[2];
    const int*   nstart_p  = (const int*)  d_in[3];
    const float* enc_w     = (const float*)d_in[4];
    const float* enc_b     = (const float*)d_in[5];
    const float* ns_w      = (const float*)d_in[6];
    const float* ns_b      = (const float*)d_in[7];
    const float* nm_w      = (const float*)d_in[8];
    const float* nm_b      = (const float*)d_in[9];
    const float* act_w     = (const float*)d_in[10];
    const float* act_b     = (const float*)d_in[11];
    const float* dec_w     = (const float*)d_in[12];
    const float* dec_b     = (const float*)d_in[13];
    float* out = (float*)d_out;

    float* feats  = (float*)d_ws;
    float* finalv = feats + NN * H;
    float* qm     = finalv + NN * H;   // QCAP*M floats ≈ 5.1 MB

    init_kernel<<<NN, 128, 0, stream>>>(xa, fm, enc_w, enc_b, nstart_p,
                                        feats, finalv, qm);
    seq_kernel<<<1, NT, 0, stream>>>(neighbors, ns_w, ns_b, nm_w, nm_b,
                                     act_w, act_b, dec_w, dec_b, nstart_p,
                                     feats, finalv, qm, out);
}